// Round 13
// baseline (1452.755 us; speedup 1.0000x reference)
//
#include <hip/hip_runtime.h>

using u16 = unsigned short;
using u32 = unsigned int;
typedef short s8v __attribute__((ext_vector_type(8)));
typedef float f4v __attribute__((ext_vector_type(4)));

#define DEV static __device__ __forceinline__

// split f32 into hi+lo bf16 (round-to-nearest-even)
DEV void cvt_split(float f, u16& h, u16& l) {
  u32 x = __builtin_bit_cast(u32, f);
  u32 rh = (x + 0x7FFFu + ((x >> 16) & 1u)) & 0xFFFF0000u;
  h = (u16)(rh >> 16);
  float fl = f - __builtin_bit_cast(float, rh);
  u32 y = __builtin_bit_cast(u32, fl);
  l = (u16)((y + 0x7FFFu + ((y >> 16) & 1u)) >> 16);
}

// ---------------- misc prep: x0 build (+ exact sqnorm) + conv3 W2 split + W1 diff precompute ----------------
__global__ void k_misc0(const float* __restrict__ x, const float* __restrict__ pos,
                        float* __restrict__ x0, float* __restrict__ sq,
                        const float* __restrict__ W2c3, u16* __restrict__ eW2h, u16* __restrict__ eW2l,
                        const float* __restrict__ W1c1, const float* __restrict__ W1c2,
                        const float* __restrict__ W1c3,
                        float* __restrict__ wd1, float* __restrict__ wd2, float* __restrict__ wd3) {
  int b = blockIdx.x;
  if (b < 64) {                       // build x0 = [pos, x], padded to 8 cols
    int p = b * 256 + threadIdx.x;
    float* o = x0 + (size_t)p * 8;
    float o0 = pos[p*3+0], o1 = pos[p*3+1], o2 = pos[p*3+2];
    float o3 = x[p*3+0],   o4 = x[p*3+1],   o5 = x[p*3+2];
    o[0] = o0; o[1] = o1; o[2] = o2;
    o[3] = o3; o[4] = o4; o[5] = o5;
    o[6] = 0.f; o[7] = 0.f;
    // exact replication of the sqnorm xor-chain with F=8 (zero lanes are +0.0, bitwise-neutral)
    float s = ((o0*o0 + o4*o4) + (o2*o2 + 0.f)) + ((o1*o1 + o5*o5) + (o3*o3 + 0.f));
    sq[p] = s;
  } else if (b < 80) {                // conv3 W2 2-way split -> [n][72]
    int e = (b - 64) * 256 + threadIdx.x;   // 0..4095
    int k = e >> 6, n = e & 63;
    u16 h, l;
    cvt_split(W2c3[e], h, l);
    eW2h[n*72 + k] = h;
    eW2l[n*72 + k] = l;
  } else if (b == 80) {               // conv1 Wd = W1a - W1b (F=6)
    for (int e = threadIdx.x; e < 6*64; e += 256) wd1[e] = W1c1[e] - W1c1[6*64 + e];
  } else if (b == 81) {               // conv2 Wd (F=64)
    for (int e = threadIdx.x; e < 64*64; e += 256) wd2[e] = W1c2[e] - W1c2[64*64 + e];
  } else {                            // conv3 Wd (F=64)
    for (int e = threadIdx.x; e < 64*64; e += 256) wd3[e] = W1c3[e] - W1c3[64*64 + e];
  }
}

// ---------------- all 3 MLP weight splits in one launch ----------------
__global__ void k_splitmlp(const float* __restrict__ W1, const float* __restrict__ W2,
                           const float* __restrict__ W3,
                           u16* __restrict__ m1h, u16* __restrict__ m1l,
                           u16* __restrict__ m2h, u16* __restrict__ m2l,
                           u16* __restrict__ m3h, u16* __restrict__ m3l) {
  int b = blockIdx.x;
  u16 h, l;
  if (b < 768) {                      // W1: 192x1024 -> [1024][200]
    int e = b * 256 + threadIdx.x;
    if (e < 192 * 1024) {
      int k = e >> 10, n = e & 1023;
      cvt_split(W1[e], h, l);
      m1h[(size_t)n*200 + k] = h; m1l[(size_t)n*200 + k] = l;
    }
  } else if (b < 1792) {              // W2: 1024x256 -> [256][1032]
    int e = (b - 768) * 256 + threadIdx.x;
    int k = e >> 8, n = e & 255;
    cvt_split(W2[e], h, l);
    m2h[(size_t)n*1032 + k] = h; m2l[(size_t)n*1032 + k] = l;
  } else {                            // W3: 256x128 -> [128][264]
    int e = (b - 1792) * 256 + threadIdx.x;
    int k = e >> 7, n = e & 127;
    cvt_split(W3[e], h, l);
    m3h[(size_t)n*264 + k] = h; m3l[(size_t)n*264 + k] = l;
  }
}

// ---------------- split activations: A[8192x192] f32 -> Ah/Al u16 (same layout) ----------------
__global__ void k_splita(const float* __restrict__ A, u16* __restrict__ Ah, u16* __restrict__ Al) {
  int e = blockIdx.x * 256 + threadIdx.x;   // 1,572,864 elements
  u16 h, l;
  cvt_split(A[e], h, l);
  Ah[e] = h; Al[e] = l;
}

// ---------------- distance GEMM: D = sq_i + sq_j - 2 * Xi . Xj ----------------
// K-chunked staging (BK=32): LDS 37.9 KB -> 4 blocks/CU. Per-thread FMA order over
// global k is the same ascending 0..F-1 sequence as unchunked => bit-identical D.
template<int F>
__global__ __launch_bounds__(256) void k_dist(const float* __restrict__ x, int stride,
    const float* __restrict__ sq, int cbase, float* __restrict__ D) {
  constexpr int BK = (F > 32) ? 32 : F;
  constexpr int PAD = BK + 4;
  __shared__ __align__(16) float Xi[128 * PAD];
  __shared__ __align__(16) float Xj[128 * PAD];
  __shared__ float SQI[128], SQJ[128];
  int b  = blockIdx.z;
  int i0 = cbase + blockIdx.y * 128;
  int j0 = blockIdx.x * 128;
  int tid = threadIdx.x;
  if (tid < 128) {
    SQI[tid] = sq[b*2048 + i0 + tid];
    SQJ[tid] = sq[b*2048 + j0 + tid];
  }
  int tx = tid & 15, ty = tid >> 4;
  float acc[8][8];
  #pragma unroll
  for (int i = 0; i < 8; ++i)
    #pragma unroll
    for (int j = 0; j < 8; ++j) acc[i][j] = 0.f;

  for (int kc = 0; kc < F; kc += BK) {
    if (kc) __syncthreads();
    constexpr int NPASS = 128 * (BK / 4) / 256;
    #pragma unroll
    for (int ps = 0; ps < NPASS; ++ps) {
      int e4 = ps * 256 + tid;
      int r = e4 / (BK / 4), f4 = (e4 % (BK / 4)) * 4;
      *(float4*)&Xi[r*PAD + f4] = *(const float4*)&x[(size_t)(b*2048 + i0 + r)*stride + kc + f4];
      *(float4*)&Xj[r*PAD + f4] = *(const float4*)&x[(size_t)(b*2048 + j0 + r)*stride + kc + f4];
    }
    __syncthreads();
    #pragma unroll 2
    for (int kf = 0; kf < BK; kf += 4) {
      float4 av[8], wv[8];
      #pragma unroll
      for (int i = 0; i < 8; ++i) av[i] = *(const float4*)&Xi[(ty + 16*i)*PAD + kf];
      #pragma unroll
      for (int j = 0; j < 8; ++j) wv[j] = *(const float4*)&Xj[(tx + 16*j)*PAD + kf];
      #pragma unroll
      for (int i = 0; i < 8; ++i)
        #pragma unroll
        for (int j = 0; j < 8; ++j) {
          acc[i][j] += av[i].x * wv[j].x;
          acc[i][j] += av[i].y * wv[j].y;
          acc[i][j] += av[i].z * wv[j].z;
          acc[i][j] += av[i].w * wv[j].w;
        }
    }
  }
  #pragma unroll
  for (int i = 0; i < 8; ++i) {
    int row = ty + 16*i;
    float si = SQI[row];
    #pragma unroll
    for (int j = 0; j < 8; ++j) {
      int col = tx + 16*j;
      D[(size_t)(b*512 + blockIdx.y*128 + row)*2048 + j0 + col] =
          si + SQJ[col] - 2.f * acc[i][j];
    }
  }
}

// ---------------- top-30 smallest per row, wave per row ----------------
__global__ __launch_bounds__(256) void k_topk(const float* __restrict__ D, int cbase,
                                              int* __restrict__ knn) {
  int wid  = blockIdx.x * 4 + (threadIdx.x >> 6);
  int lane = threadIdx.x & 63;
  int b = wid >> 9, il = wid & 511;
  const float* row = D + (size_t)(b*512 + il) * 2048;
  float v[32];
  #pragma unroll
  for (int s = 0; s < 32; ++s) v[s] = row[lane + 64*s];
  const float INFV = __builtin_bit_cast(float, 0x7f800000u);
  int wj = 0;
  #pragma unroll 1
  for (int it = 0; it < 30; ++it) {
    float mv = v[0]; int ms = 0;
    #pragma unroll
    for (int s = 1; s < 32; ++s) {
      bool lt = v[s] < mv;
      mv = lt ? v[s] : mv;
      ms = lt ? s : ms;
    }
    int mj = lane + (ms << 6);
    #pragma unroll
    for (int m = 1; m < 64; m <<= 1) {
      float ov = __shfl_xor(mv, m);
      int   oj = __shfl_xor(mj, m);
      bool take = (ov < mv) || ((ov == mv) && (oj < mj));
      mv = take ? ov : mv;
      mj = take ? oj : mj;
    }
    int gj = __builtin_amdgcn_readfirstlane(mj);
    if (lane == it) wj = gj;
    int owner = gj & 63, slot = gj >> 6;
    #pragma unroll
    for (int s = 0; s < 32; ++s) {
      if (slot == s) {
        if (lane == owner) v[s] = INFV;
      }
    }
  }
  if (lane < 30) knn[(size_t)(b*2048 + cbase + il)*30 + lane] = b*2048 + wj;
}

// ---------------- per-point precompute: A0 = xi@Wd+b1, V = x@W1b (Wd = W1a-W1b precomputed) ----------------
__global__ __launch_bounds__(256, 4) void k_prep(const float* __restrict__ x, int stride, int F,
    const float* __restrict__ Wd, const float* __restrict__ W1, const float* __restrict__ b1,
    float* __restrict__ A0, float* __restrict__ V) {
  int p = blockIdx.x * 4 + (threadIdx.x >> 6);
  int lane = threadIdx.x & 63;
  float u = 0.f, v = 0.f;
  for (int f = 0; f < F; ++f) {
    float xv = x[(size_t)p*stride + f];
    float wd = Wd[f*64 + lane];            // same bits as (wa - wb)
    float wb = W1[(F + f)*64 + lane];
    u += xv * wd;
    v += xv * wb;
  }
  A0[p*64 + lane] = u + b1[lane];
  V[p*64 + lane]  = v;
}

// ---------------- edge conv, f32, bit-identical chains (round-9 form) + fused sqnorm ----------------
// wave = 1 point. W2 column load at top (round-9 proven schedule); phase 1 (lane=c) h1->LDS;
// phase 2 (lane=c') broadcast ds_read_b128 + FMA; epilogue emits exact sqnorm chain.
__global__ __launch_bounds__(256) void k_edge_b(const float* __restrict__ A0,
    const float* __restrict__ V, const int* __restrict__ knn,
    const float* __restrict__ W2, const float* __restrict__ b2,
    const float* __restrict__ g, const float* __restrict__ be,
    float* __restrict__ out, int ostride, float* __restrict__ sqout) {
  __shared__ __align__(16) float h1s[4][30][68];
  int wave = threadIdx.x >> 6, lane = threadIdx.x & 63;
  int p = blockIdx.x * 4 + wave;

  // W2 column for this lane (c' = lane) -- round-9 placement
  float w2c[64];
  #pragma unroll
  for (int c = 0; c < 64; ++c) w2c[c] = W2[c*64 + lane];

  float a0 = A0[(size_t)p*64 + lane];
  float gg = g[lane], bbe = be[lane];
  const int* kr = knn + (size_t)p*30;

  // phase 1: lane = input channel c; h1 = relu((A0+V_j)*g+be) -- identical expression
  #pragma unroll 2
  for (int k = 0; k < 30; ++k) {
    int j = kr[k];
    float v = V[(size_t)j*64 + lane];
    float pre = (a0 + v) * gg + bbe;
    h1s[wave][k][lane] = pre > 0.f ? pre : 0.f;
  }
  // no barrier needed: each wave reads only its own h1s[wave] slice (in-wave LDS ordering)

  // phase 2: lane = c'; identical s0..s3 chains + ascending-k fmax
  float m = -3.0e38f;
  #pragma unroll 1
  for (int k = 0; k < 30; ++k) {
    float s0 = 0.f, s1 = 0.f, s2 = 0.f, s3 = 0.f;
    #pragma unroll
    for (int c = 0; c < 64; c += 4) {
      float4 hv = *(const float4*)&h1s[wave][k][c];   // broadcast read
      s0 += hv.x * w2c[c+0];
      s1 += hv.y * w2c[c+1];
      s2 += hv.z * w2c[c+2];
      s3 += hv.w * w2c[c+3];
    }
    float h2 = (s0 + s1) + (s2 + s3);
    m = m > h2 ? m : h2;
  }
  float ov = m + b2[lane];
  out[(size_t)p*ostride + lane] = ov;

  // sq of output row: exact replication of the sqnorm shuffle chain (validated round 12)
  float s = ov * ov;
  #pragma unroll
  for (int mm = 32; mm; mm >>= 1) s += __shfl_xor(s, mm);
  if (lane == 0) sqout[p] = s;
}

// ---------------- edge conv via MFMA (3-product split-bf16; conv3 only) ----------------
__global__ __launch_bounds__(256) void k_edge_m(const float* __restrict__ A0,
    const float* __restrict__ V, const int* __restrict__ knn,
    const u16* __restrict__ W2h, const u16* __restrict__ W2l,
    const float* __restrict__ b2,
    const float* __restrict__ g, const float* __restrict__ be,
    float* __restrict__ out, int ostride) {
  constexpr int PKW = 72;
  int p = blockIdx.x * 4 + (threadIdx.x >> 6);
  int lane = threadIdx.x & 63;
  int lr = lane & 15, kb = lane >> 4;

  const int* kr = knn + (size_t)p * 30;
  int j0 = kr[lr];
  int j1 = kr[lr + 16 < 30 ? lr + 16 : 29];

  s8v bh[4][2], bl[4][2];
  #pragma unroll
  for (int jf = 0; jf < 4; ++jf) {
    int n = jf*16 + lr;
    #pragma unroll
    for (int ks = 0; ks < 2; ++ks) {
      bh[jf][ks] = *(const s8v*)&W2h[n*PKW + ks*32 + kb*8];
      bl[jf][ks] = *(const s8v*)&W2l[n*PKW + ks*32 + kb*8];
    }
  }

  float base[2][8], gs[2][8];
  #pragma unroll
  for (int ks = 0; ks < 2; ++ks) {
    int cb = ks*32 + kb*8;
    float4 a0 = *(const float4*)&A0[(size_t)p*64 + cb];
    float4 a1 = *(const float4*)&A0[(size_t)p*64 + cb + 4];
    float4 g0 = *(const float4*)&g[cb];
    float4 g1 = *(const float4*)&g[cb + 4];
    float4 e0 = *(const float4*)&be[cb];
    float4 e1 = *(const float4*)&be[cb + 4];
    base[ks][0]=a0.x*g0.x+e0.x; base[ks][1]=a0.y*g0.y+e0.y;
    base[ks][2]=a0.z*g0.z+e0.z; base[ks][3]=a0.w*g0.w+e0.w;
    base[ks][4]=a1.x*g1.x+e1.x; base[ks][5]=a1.y*g1.y+e1.y;
    base[ks][6]=a1.z*g1.z+e1.z; base[ks][7]=a1.w*g1.w+e1.w;
    gs[ks][0]=g0.x; gs[ks][1]=g0.y; gs[ks][2]=g0.z; gs[ks][3]=g0.w;
    gs[ks][4]=g1.x; gs[ks][5]=g1.y; gs[ks][6]=g1.z; gs[ks][7]=g1.w;
  }

  s8v ah[2][2], al[2][2];
  #pragma unroll
  for (int mt = 0; mt < 2; ++mt) {
    const float* vr = V + (size_t)(mt ? j1 : j0) * 64;
    #pragma unroll
    for (int ks = 0; ks < 2; ++ks) {
      int cb = ks*32 + kb*8;
      float4 v0 = *(const float4*)&vr[cb];
      float4 v1 = *(const float4*)&vr[cb + 4];
      float hv[8];
      hv[0]=base[ks][0]+v0.x*gs[ks][0]; hv[1]=base[ks][1]+v0.y*gs[ks][1];
      hv[2]=base[ks][2]+v0.z*gs[ks][2]; hv[3]=base[ks][3]+v0.w*gs[ks][3];
      hv[4]=base[ks][4]+v1.x*gs[ks][4]; hv[5]=base[ks][5]+v1.y*gs[ks][5];
      hv[6]=base[ks][6]+v1.z*gs[ks][6]; hv[7]=base[ks][7]+v1.w*gs[ks][7];
      s8v hfrag, lfrag;
      #pragma unroll
      for (int e = 0; e < 8; ++e) {
        float h1 = hv[e] > 0.f ? hv[e] : 0.f;
        u16 hh, ll;
        cvt_split(h1, hh, ll);
        hfrag[e] = (short)hh; lfrag[e] = (short)ll;
      }
      ah[mt][ks] = hfrag; al[mt][ks] = lfrag;
    }
  }

  f4v acc[2][4];
  #pragma unroll
  for (int mt = 0; mt < 2; ++mt)
    #pragma unroll
    for (int jf = 0; jf < 4; ++jf) acc[mt][jf] = (f4v)(0.f);

  #pragma unroll
  for (int mt = 0; mt < 2; ++mt)
    #pragma unroll
    for (int jf = 0; jf < 4; ++jf)
      #pragma unroll
      for (int ks = 0; ks < 2; ++ks) {
        acc[mt][jf] = __builtin_amdgcn_mfma_f32_16x16x32_bf16(ah[mt][ks], bh[jf][ks], acc[mt][jf], 0, 0, 0);
        acc[mt][jf] = __builtin_amdgcn_mfma_f32_16x16x32_bf16(ah[mt][ks], bl[jf][ks], acc[mt][jf], 0, 0, 0);
        acc[mt][jf] = __builtin_amdgcn_mfma_f32_16x16x32_bf16(al[mt][ks], bh[jf][ks], acc[mt][jf], 0, 0, 0);
      }

  #pragma unroll
  for (int jf = 0; jf < 4; ++jf) {
    float m = fmaxf(fmaxf(acc[0][jf][0], acc[0][jf][1]), fmaxf(acc[0][jf][2], acc[0][jf][3]));
    float m1 = fmaxf(fmaxf(acc[1][jf][0], acc[1][jf][1]), fmaxf(acc[1][jf][2], acc[1][jf][3]));
    m = fmaxf(m, m1);
    m = fmaxf(m, __shfl_xor(m, 16));
    m = fmaxf(m, __shfl_xor(m, 32));
    if (kb == 0) out[(size_t)p*ostride + jf*16 + lr] = m + b2[jf*16 + lr];
  }
}

// ---------------- split-bf16 MFMA GEMM v2: no LDS, pre-split A and W, fragments from L2 ----------------
// C = relu(A@W + b); SPLIT=1: write u16 hi/lo pair (feeds next layer); SPLIT=0: write f32
template<int NJF, int SPLIT>
__global__ __launch_bounds__(256) void k_mlp(
    const u16* __restrict__ Ahg, const u16* __restrict__ Alg, int lka,
    const u16* __restrict__ Wth, const u16* __restrict__ Wtl, int PKW,
    const float* __restrict__ bg,
    float* __restrict__ Cf, u16* __restrict__ Ch, u16* __restrict__ Cl,
    int ldc, int K) {
  int tid  = threadIdx.x;
  int wave = tid >> 6, lane = tid & 63;
  int wm = (wave >> 1) * 64, wn = (wave & 1) * (NJF*16);
  int lr = lane & 15, kb = lane >> 4;
  int m0 = blockIdx.y * 128, n0 = blockIdx.x * (2*NJF*16);

  f4v acc[4][NJF];
  #pragma unroll
  for (int i = 0; i < 4; ++i)
    #pragma unroll
    for (int j = 0; j < NJF; ++j) acc[i][j] = (f4v)(0.f);

  for (int k0 = 0; k0 < K; k0 += 32) {
    s8v bh[NJF], bl[NJF], ah[4], al[4];
    #pragma unroll
    for (int jf = 0; jf < NJF; ++jf) {
      int n = n0 + wn + jf*16 + lr;
      bh[jf] = *(const s8v*)&Wth[(size_t)n*PKW + k0 + kb*8];
      bl[jf] = *(const s8v*)&Wtl[(size_t)n*PKW + k0 + kb*8];
    }
    #pragma unroll
    for (int mf = 0; mf < 4; ++mf) {
      size_t a = (size_t)(m0 + wm + mf*16 + lr)*lka + k0 + kb*8;
      ah[mf] = *(const s8v*)&Ahg[a];
      al[mf] = *(const s8v*)&Alg[a];
    }
    #pragma unroll
    for (int mf = 0; mf < 4; ++mf)
      #pragma unroll
      for (int jf = 0; jf < NJF; ++jf) {
        acc[mf][jf] = __builtin_amdgcn_mfma_f32_16x16x32_bf16(ah[mf], bh[jf], acc[mf][jf], 0, 0, 0);
        acc[mf][jf] = __builtin_amdgcn_mfma_f32_16x16x32_bf16(ah[mf], bl[jf], acc[mf][jf], 0, 0, 0);
        acc[mf][jf] = __builtin_amdgcn_mfma_f32_16x16x32_bf16(al[mf], bh[jf], acc[mf][jf], 0, 0, 0);
      }
  }

  #pragma unroll
  for (int jf = 0; jf < NJF; ++jf) {
    int n = n0 + wn + jf*16 + lr;
    float bb = bg[n];
    #pragma unroll
    for (int mf = 0; mf < 4; ++mf) {
      #pragma unroll
      for (int r = 0; r < 4; ++r) {
        int m = m0 + wm + mf*16 + kb*4 + r;
        float v = acc[mf][jf][r] + bb;
        v = v > 0.f ? v : 0.f;
        if (SPLIT) {
          u16 h, l;
          cvt_split(v, h, l);
          Ch[(size_t)m*ldc + n] = h;
          Cl[(size_t)m*ldc + n] = l;
        } else {
          Cf[(size_t)m*ldc + n] = v;
        }
      }
    }
  }
}

// ---------------- head: 128->13 + log_softmax, lane per point ----------------
__global__ __launch_bounds__(256) void k_head(const float* __restrict__ H3,
    const float* __restrict__ W4, const float* __restrict__ b4,
    float* __restrict__ out0, int pbase) {
  __shared__ float w4s[128 * 13];
  __shared__ float b4s[13];
  for (int e = threadIdx.x; e < 128*13; e += 256) w4s[e] = W4[e];
  if (threadIdx.x < 13) b4s[threadIdx.x] = b4[threadIdx.x];
  __syncthreads();
  int pl = blockIdx.x * 256 + threadIdx.x;
  float acc[13];
  #pragma unroll
  for (int c = 0; c < 13; ++c) acc[c] = b4s[c];
  const float* hr = H3 + (size_t)pl * 128;
  #pragma unroll 1
  for (int k = 0; k < 128; k += 4) {
    float4 h = *(const float4*)&hr[k];
    #pragma unroll
    for (int c = 0; c < 13; ++c) {
      acc[c] += h.x * w4s[(k+0)*13 + c];
      acc[c] += h.y * w4s[(k+1)*13 + c];
      acc[c] += h.z * w4s[(k+2)*13 + c];
      acc[c] += h.w * w4s[(k+3)*13 + c];
    }
  }
  float mx = acc[0];
  #pragma unroll
  for (int c = 1; c < 13; ++c) mx = fmaxf(mx, acc[c]);
  float s = 0.f;
  #pragma unroll
  for (int c = 0; c < 13; ++c) s += expf(acc[c] - mx);
  float lg = logf(s);
  size_t ob = (size_t)(pbase + pl) * 13;
  #pragma unroll
  for (int c = 0; c < 13; ++c) out0[ob + c] = acc[c] - mx - lg;
}

// ---------------- out1 = x3 ----------------
__global__ void k_out1(const float* __restrict__ hcat, float* __restrict__ out1) {
  int e = blockIdx.x * 256 + threadIdx.x;
  int p = e >> 6, c = e & 63;
  out1[e] = hcat[(size_t)p*192 + 128 + c];
}

extern "C" void kernel_launch(void* const* d_in, const int* in_sizes, int n_in,
                              void* d_out, int out_size, void* d_ws, size_t ws_size,
                              hipStream_t stream) {
  (void)in_sizes; (void)n_in; (void)out_size; (void)ws_size;
  const float* x   = (const float*)d_in[0];
  const float* pos = (const float*)d_in[1];
  const float* cw[3][6];   // W1,b1,g,be,W2,b2 per conv
  for (int c = 0; c < 3; ++c)
    for (int t = 0; t < 6; ++t)
      cw[c][t] = (const float*)d_in[3 + c*6 + t];
  const float *mW[4], *mb[4];
  for (int j = 0; j < 4; ++j) {
    mW[j] = (const float*)d_in[21 + 2*j];
    mb[j] = (const float*)d_in[22 + 2*j];
  }

  float* ws   = (float*)d_ws;
  float* x0   = ws;                        // 131072
  float* sq   = x0 + 131072;               // 16384
  int*   knn  = (int*)(sq + 16384);        // 491520 ints
  float* A0   = (float*)(knn + 491520);    // 1048576 (4 MB)
  float* V    = A0 + 1048576;              // 1048576 (4 MB)
  float* hcat = V + 1048576;               // 3145728 (x1|x2|x3, stride 192)
  float* U    = hcat + 3145728;            // 8388608 (D chunks; later H1h|H1l u16)
  float* H2c  = U + 8388608;               // 2097152 (H2h|H2l u16)
  float* H3c  = H2c + 2097152;             // 1048576 (f32, head input)
  u16*   eW2  = (u16*)(H3c + 1048576);     // conv3 W2 split: 2 x 4608 u16
  float* wd1  = (float*)(eW2 + 9216);      // conv1 Wd: 384
  float* wd2  = wd1 + 384;                 // conv2 Wd: 4096
  float* wd3  = wd2 + 4096;                // conv3 Wd: 4096

  // MLP weight splits: second half of V region (dead after conv phase)
  u16* mwp = (u16*)(V + 524288);           // 2 MB area
  u16* m1h = mwp;            u16* m1l = m1h + 204800;   // [1024][200]
  u16* m2h = m1l + 204800;   u16* m2l = m2h + 264192;   // [256][1032]
  u16* m3h = m2l + 264192;   u16* m3l = m3h + 33792;    // [128][264]
  // per-ch activation split: A0 region + first half of V (dead after conv phase)
  u16* Aih = (u16*)A0;                     // 8192*192 u16
  u16* Ail = Aih + 1572864;                // ends exactly at V + 524288 floats
  // H1/H2 splits
  u16* H1h = (u16*)U;        u16* H1l = H1h + 8388608;  // [8192][1024] each
  u16* H2h = (u16*)H2c;      u16* H2l = H2h + 2097152;  // [8192][256] each

  float* out0 = (float*)d_out;
  float* out1 = out0 + 8*2048*13;

  k_misc0<<<83, 256, 0, stream>>>(x, pos, x0, sq, cw[2][4], eW2, eW2 + 4608,
                                  cw[0][0], cw[1][0], cw[2][0], wd1, wd2, wd3);

  for (int c = 0; c < 3; ++c) {
    const float* xin; const float* wdc; int stride, F;
    if (c == 0)      { xin = x0;        wdc = wd1; stride = 8;   F = 6;  }
    else if (c == 1) { xin = hcat;      wdc = wd2; stride = 192; F = 64; }
    else             { xin = hcat + 64; wdc = wd3; stride = 192; F = 64; }
    // sq is produced by k_misc0 (conv1) or the previous conv's k_edge_b epilogue
    for (int ch = 0; ch < 4; ++ch) {
      if (c == 0) k_dist<8> <<<dim3(16,4,8), 256, 0, stream>>>(xin, stride, sq, ch*512, U);
      else        k_dist<64><<<dim3(16,4,8), 256, 0, stream>>>(xin, stride, sq, ch*512, U);
      k_topk<<<1024, 256, 0, stream>>>(U, ch*512, knn);
    }
    k_prep<<<4096, 256, 0, stream>>>(xin, stride, F, wdc, cw[c][0], cw[c][1], A0, V);
    if (c < 2)
      k_edge_b<<<4096, 256, 0, stream>>>(A0, V, knn, cw[c][4], cw[c][5],
                                         cw[c][2], cw[c][3], hcat + 64*c, 192, sq);
    else
      k_edge_m<<<4096, 256, 0, stream>>>(A0, V, knn, eW2, eW2 + 4608,
                                         cw[c][5], cw[c][2], cw[c][3], hcat + 64*c, 192);
  }

  // split MLP weights (V region second half now dead)
  k_splitmlp<<<1920, 256, 0, stream>>>(mW[0], mW[1], mW[2], m1h, m1l, m2h, m2l, m3h, m3l);

  for (int ch = 0; ch < 2; ++ch) {
    k_splita<<<6144, 256, 0, stream>>>(hcat + (size_t)ch * 8192 * 192, Aih, Ail);
    k_mlp<4,1><<<dim3(8,64), 256, 0, stream>>>(Aih, Ail, 192,  m1h, m1l, 200,  mb[0],
                                               nullptr, H1h, H1l, 1024, 192);
    k_mlp<2,1><<<dim3(4,64), 256, 0, stream>>>(H1h, H1l, 1024, m2h, m2l, 1032, mb[1],
                                               nullptr, H2h, H2l, 256, 1024);
    k_mlp<2,0><<<dim3(2,64), 256, 0, stream>>>(H2h, H2l, 256,  m3h, m3l, 264,  mb[2],
                                               H3c, nullptr, nullptr, 128, 256);
    k_head<<<32, 256, 0, stream>>>(H3c, mW[3], mb[3], out0, ch*8192);
  }
  k_out1<<<4096, 256, 0, stream>>>(hcat, out1);
}

// Round 14
// 1349.256 us; speedup vs baseline: 1.0767x; 1.0767x over previous
//
#include <hip/hip_runtime.h>

using u16 = unsigned short;
using u32 = unsigned int;
typedef short s8v __attribute__((ext_vector_type(8)));
typedef float f4v __attribute__((ext_vector_type(4)));

#define DEV static __device__ __forceinline__

// split f32 into hi+lo bf16 (round-to-nearest-even)
DEV void cvt_split(float f, u16& h, u16& l) {
  u32 x = __builtin_bit_cast(u32, f);
  u32 rh = (x + 0x7FFFu + ((x >> 16) & 1u)) & 0xFFFF0000u;
  h = (u16)(rh >> 16);
  float fl = f - __builtin_bit_cast(float, rh);
  u32 y = __builtin_bit_cast(u32, fl);
  l = (u16)((y + 0x7FFFu + ((y >> 16) & 1u)) >> 16);
}

// ---------------- misc prep: x0 build (+ exact sqnorm) + conv3 W2 split + W1 diff precompute ----------------
__global__ void k_misc0(const float* __restrict__ x, const float* __restrict__ pos,
                        float* __restrict__ x0, float* __restrict__ sq,
                        const float* __restrict__ W2c3, u16* __restrict__ eW2h, u16* __restrict__ eW2l,
                        const float* __restrict__ W1c1, const float* __restrict__ W1c2,
                        const float* __restrict__ W1c3,
                        float* __restrict__ wd1, float* __restrict__ wd2, float* __restrict__ wd3) {
  int b = blockIdx.x;
  if (b < 64) {                       // build x0 = [pos, x], padded to 8 cols
    int p = b * 256 + threadIdx.x;
    float* o = x0 + (size_t)p * 8;
    float o0 = pos[p*3+0], o1 = pos[p*3+1], o2 = pos[p*3+2];
    float o3 = x[p*3+0],   o4 = x[p*3+1],   o5 = x[p*3+2];
    o[0] = o0; o[1] = o1; o[2] = o2;
    o[3] = o3; o[4] = o4; o[5] = o5;
    o[6] = 0.f; o[7] = 0.f;
    // exact replication of the sqnorm xor-chain with F=8 (zero lanes are +0.0, bitwise-neutral)
    float s = ((o0*o0 + o4*o4) + (o2*o2 + 0.f)) + ((o1*o1 + o5*o5) + (o3*o3 + 0.f));
    sq[p] = s;
  } else if (b < 80) {                // conv3 W2 2-way split -> [n][72]
    int e = (b - 64) * 256 + threadIdx.x;   // 0..4095
    int k = e >> 6, n = e & 63;
    u16 h, l;
    cvt_split(W2c3[e], h, l);
    eW2h[n*72 + k] = h;
    eW2l[n*72 + k] = l;
  } else if (b == 80) {               // conv1 Wd = W1a - W1b (F=6)
    for (int e = threadIdx.x; e < 6*64; e += 256) wd1[e] = W1c1[e] - W1c1[6*64 + e];
  } else if (b == 81) {               // conv2 Wd (F=64)
    for (int e = threadIdx.x; e < 64*64; e += 256) wd2[e] = W1c2[e] - W1c2[64*64 + e];
  } else {                            // conv3 Wd (F=64)
    for (int e = threadIdx.x; e < 64*64; e += 256) wd3[e] = W1c3[e] - W1c3[64*64 + e];
  }
}

// ---------------- all 3 MLP weight splits in one launch ----------------
__global__ void k_splitmlp(const float* __restrict__ W1, const float* __restrict__ W2,
                           const float* __restrict__ W3,
                           u16* __restrict__ m1h, u16* __restrict__ m1l,
                           u16* __restrict__ m2h, u16* __restrict__ m2l,
                           u16* __restrict__ m3h, u16* __restrict__ m3l) {
  int b = blockIdx.x;
  u16 h, l;
  if (b < 768) {                      // W1: 192x1024 -> [1024][200]
    int e = b * 256 + threadIdx.x;
    if (e < 192 * 1024) {
      int k = e >> 10, n = e & 1023;
      cvt_split(W1[e], h, l);
      m1h[(size_t)n*200 + k] = h; m1l[(size_t)n*200 + k] = l;
    }
  } else if (b < 1792) {              // W2: 1024x256 -> [256][1032]
    int e = (b - 768) * 256 + threadIdx.x;
    int k = e >> 8, n = e & 255;
    cvt_split(W2[e], h, l);
    m2h[(size_t)n*1032 + k] = h; m2l[(size_t)n*1032 + k] = l;
  } else {                            // W3: 256x128 -> [128][264]
    int e = (b - 1792) * 256 + threadIdx.x;
    int k = e >> 7, n = e & 127;
    cvt_split(W3[e], h, l);
    m3h[(size_t)n*264 + k] = h; m3l[(size_t)n*264 + k] = l;
  }
}

// ---------------- split activations: A[8192x192] f32 -> Ah/Al u16 (same layout) ----------------
__global__ void k_splita(const float* __restrict__ A, u16* __restrict__ Ah, u16* __restrict__ Al) {
  int e = blockIdx.x * 256 + threadIdx.x;   // 1,572,864 elements
  u16 h, l;
  cvt_split(A[e], h, l);
  Ah[e] = h; Al[e] = l;
}

// ---------------- squared norms, wave per point ----------------
__global__ void k_sqnorm(const float* __restrict__ x, int stride, int F,
                         float* __restrict__ sq) {
  int wid  = (blockIdx.x * 256 + threadIdx.x) >> 6;
  int lane = threadIdx.x & 63;
  float v = (lane < F) ? x[(size_t)wid * stride + lane] : 0.f;
  float s = v * v;
  #pragma unroll
  for (int m = 32; m; m >>= 1) s += __shfl_xor(s, m);
  if (lane == 0) sq[wid] = s;
}

// ---------------- distance GEMM: D = sq_i + sq_j - 2 * Xi . Xj ----------------
// K-chunked staging (BK=32): LDS 37.9 KB -> 4 blocks/CU. Per-thread FMA order over
// global k is the same ascending 0..F-1 sequence as unchunked => bit-identical D.
template<int F>
__global__ __launch_bounds__(256) void k_dist(const float* __restrict__ x, int stride,
    const float* __restrict__ sq, int cbase, float* __restrict__ D) {
  constexpr int BK = (F > 32) ? 32 : F;
  constexpr int PAD = BK + 4;
  __shared__ __align__(16) float Xi[128 * PAD];
  __shared__ __align__(16) float Xj[128 * PAD];
  __shared__ float SQI[128], SQJ[128];
  int b  = blockIdx.z;
  int i0 = cbase + blockIdx.y * 128;
  int j0 = blockIdx.x * 128;
  int tid = threadIdx.x;
  if (tid < 128) {
    SQI[tid] = sq[b*2048 + i0 + tid];
    SQJ[tid] = sq[b*2048 + j0 + tid];
  }
  int tx = tid & 15, ty = tid >> 4;
  float acc[8][8];
  #pragma unroll
  for (int i = 0; i < 8; ++i)
    #pragma unroll
    for (int j = 0; j < 8; ++j) acc[i][j] = 0.f;

  for (int kc = 0; kc < F; kc += BK) {
    if (kc) __syncthreads();
    constexpr int NPASS = 128 * (BK / 4) / 256;
    #pragma unroll
    for (int ps = 0; ps < NPASS; ++ps) {
      int e4 = ps * 256 + tid;
      int r = e4 / (BK / 4), f4 = (e4 % (BK / 4)) * 4;
      *(float4*)&Xi[r*PAD + f4] = *(const float4*)&x[(size_t)(b*2048 + i0 + r)*stride + kc + f4];
      *(float4*)&Xj[r*PAD + f4] = *(const float4*)&x[(size_t)(b*2048 + j0 + r)*stride + kc + f4];
    }
    __syncthreads();
    #pragma unroll 2
    for (int kf = 0; kf < BK; kf += 4) {
      float4 av[8], wv[8];
      #pragma unroll
      for (int i = 0; i < 8; ++i) av[i] = *(const float4*)&Xi[(ty + 16*i)*PAD + kf];
      #pragma unroll
      for (int j = 0; j < 8; ++j) wv[j] = *(const float4*)&Xj[(tx + 16*j)*PAD + kf];
      #pragma unroll
      for (int i = 0; i < 8; ++i)
        #pragma unroll
        for (int j = 0; j < 8; ++j) {
          acc[i][j] += av[i].x * wv[j].x;
          acc[i][j] += av[i].y * wv[j].y;
          acc[i][j] += av[i].z * wv[j].z;
          acc[i][j] += av[i].w * wv[j].w;
        }
    }
  }
  #pragma unroll
  for (int i = 0; i < 8; ++i) {
    int row = ty + 16*i;
    float si = SQI[row];
    #pragma unroll
    for (int j = 0; j < 8; ++j) {
      int col = tx + 16*j;
      D[(size_t)(b*512 + blockIdx.y*128 + row)*2048 + j0 + col] =
          si + SQJ[col] - 2.f * acc[i][j];
    }
  }
}

// ---------------- top-30 smallest per row, wave per row ----------------
__global__ __launch_bounds__(256) void k_topk(const float* __restrict__ D, int cbase,
                                              int* __restrict__ knn) {
  int wid  = blockIdx.x * 4 + (threadIdx.x >> 6);
  int lane = threadIdx.x & 63;
  int b = wid >> 9, il = wid & 511;
  const float* row = D + (size_t)(b*512 + il) * 2048;
  float v[32];
  #pragma unroll
  for (int s = 0; s < 32; ++s) v[s] = row[lane + 64*s];
  const float INFV = __builtin_bit_cast(float, 0x7f800000u);
  int wj = 0;
  #pragma unroll 1
  for (int it = 0; it < 30; ++it) {
    float mv = v[0]; int ms = 0;
    #pragma unroll
    for (int s = 1; s < 32; ++s) {
      bool lt = v[s] < mv;
      mv = lt ? v[s] : mv;
      ms = lt ? s : ms;
    }
    int mj = lane + (ms << 6);
    #pragma unroll
    for (int m = 1; m < 64; m <<= 1) {
      float ov = __shfl_xor(mv, m);
      int   oj = __shfl_xor(mj, m);
      bool take = (ov < mv) || ((ov == mv) && (oj < mj));
      mv = take ? ov : mv;
      mj = take ? oj : mj;
    }
    int gj = __builtin_amdgcn_readfirstlane(mj);
    if (lane == it) wj = gj;
    int owner = gj & 63, slot = gj >> 6;
    #pragma unroll
    for (int s = 0; s < 32; ++s) {
      if (slot == s) {
        if (lane == owner) v[s] = INFV;
      }
    }
  }
  if (lane < 30) knn[(size_t)(b*2048 + cbase + il)*30 + lane] = b*2048 + wj;
}

// ---------------- per-point precompute: A0 = xi@Wd+b1, V = x@W1b (Wd = W1a-W1b precomputed) ----------------
__global__ __launch_bounds__(256, 4) void k_prep(const float* __restrict__ x, int stride, int F,
    const float* __restrict__ Wd, const float* __restrict__ W1, const float* __restrict__ b1,
    float* __restrict__ A0, float* __restrict__ V) {
  int p = blockIdx.x * 4 + (threadIdx.x >> 6);
  int lane = threadIdx.x & 63;
  float u = 0.f, v = 0.f;
  for (int f = 0; f < F; ++f) {
    float xv = x[(size_t)p*stride + f];
    float wd = Wd[f*64 + lane];            // same bits as (wa - wb)
    float wb = W1[(F + f)*64 + lane];
    u += xv * wd;
    v += xv * wb;
  }
  A0[p*64 + lane] = u + b1[lane];
  V[p*64 + lane]  = v;
}

// ---------------- edge conv, f32, bit-identical chains (exact round-9 form + full phase-1 unroll) ----------------
// wave = 1 point. W2 column in VGPRs (round-9 schedule); phase 1 (lane=c) h1->LDS, all 30
// gathers issued together (latency amortized); phase 2 (lane=c') broadcast ds_read_b128 + FMA.
__global__ __launch_bounds__(256, 4) void k_edge_b(const float* __restrict__ A0,
    const float* __restrict__ V, const int* __restrict__ knn,
    const float* __restrict__ W2, const float* __restrict__ b2,
    const float* __restrict__ g, const float* __restrict__ be,
    float* __restrict__ out, int ostride) {
  __shared__ __align__(16) float h1s[4][30][68];
  int wave = threadIdx.x >> 6, lane = threadIdx.x & 63;
  int p = blockIdx.x * 4 + wave;

  // W2 column for this lane (c' = lane) -- round-9 placement
  float w2c[64];
  #pragma unroll
  for (int c = 0; c < 64; ++c) w2c[c] = W2[c*64 + lane];

  float a0 = A0[(size_t)p*64 + lane];
  float gg = g[lane], bbe = be[lane];
  const int* kr = knn + (size_t)p*30;

  // phase 1: lane = input channel c; h1 = relu((A0+V_j)*g+be) -- identical expression;
  // FULL unroll: all 30 independent V-row gathers issue together (latency hiding)
  #pragma unroll
  for (int k = 0; k < 30; ++k) {
    int j = kr[k];
    float v = V[(size_t)j*64 + lane];
    float pre = (a0 + v) * gg + bbe;
    h1s[wave][k][lane] = pre > 0.f ? pre : 0.f;
  }
  // no barrier needed: each wave reads only its own h1s[wave] slice (in-wave LDS ordering)

  // phase 2: lane = c'; identical s0..s3 chains + ascending-k fmax
  float m = -3.0e38f;
  #pragma unroll 1
  for (int k = 0; k < 30; ++k) {
    float s0 = 0.f, s1 = 0.f, s2 = 0.f, s3 = 0.f;
    #pragma unroll
    for (int c = 0; c < 64; c += 4) {
      float4 hv = *(const float4*)&h1s[wave][k][c];   // broadcast read
      s0 += hv.x * w2c[c+0];
      s1 += hv.y * w2c[c+1];
      s2 += hv.z * w2c[c+2];
      s3 += hv.w * w2c[c+3];
    }
    float h2 = (s0 + s1) + (s2 + s3);
    m = m > h2 ? m : h2;
  }
  out[(size_t)p*ostride + lane] = m + b2[lane];
}

// ---------------- edge conv via MFMA (3-product split-bf16; conv3 only) ----------------
__global__ __launch_bounds__(256) void k_edge_m(const float* __restrict__ A0,
    const float* __restrict__ V, const int* __restrict__ knn,
    const u16* __restrict__ W2h, const u16* __restrict__ W2l,
    const float* __restrict__ b2,
    const float* __restrict__ g, const float* __restrict__ be,
    float* __restrict__ out, int ostride) {
  constexpr int PKW = 72;
  int p = blockIdx.x * 4 + (threadIdx.x >> 6);
  int lane = threadIdx.x & 63;
  int lr = lane & 15, kb = lane >> 4;

  const int* kr = knn + (size_t)p * 30;
  int j0 = kr[lr];
  int j1 = kr[lr + 16 < 30 ? lr + 16 : 29];

  s8v bh[4][2], bl[4][2];
  #pragma unroll
  for (int jf = 0; jf < 4; ++jf) {
    int n = jf*16 + lr;
    #pragma unroll
    for (int ks = 0; ks < 2; ++ks) {
      bh[jf][ks] = *(const s8v*)&W2h[n*PKW + ks*32 + kb*8];
      bl[jf][ks] = *(const s8v*)&W2l[n*PKW + ks*32 + kb*8];
    }
  }

  float base[2][8], gs[2][8];
  #pragma unroll
  for (int ks = 0; ks < 2; ++ks) {
    int cb = ks*32 + kb*8;
    float4 a0 = *(const float4*)&A0[(size_t)p*64 + cb];
    float4 a1 = *(const float4*)&A0[(size_t)p*64 + cb + 4];
    float4 g0 = *(const float4*)&g[cb];
    float4 g1 = *(const float4*)&g[cb + 4];
    float4 e0 = *(const float4*)&be[cb];
    float4 e1 = *(const float4*)&be[cb + 4];
    base[ks][0]=a0.x*g0.x+e0.x; base[ks][1]=a0.y*g0.y+e0.y;
    base[ks][2]=a0.z*g0.z+e0.z; base[ks][3]=a0.w*g0.w+e0.w;
    base[ks][4]=a1.x*g1.x+e1.x; base[ks][5]=a1.y*g1.y+e1.y;
    base[ks][6]=a1.z*g1.z+e1.z; base[ks][7]=a1.w*g1.w+e1.w;
    gs[ks][0]=g0.x; gs[ks][1]=g0.y; gs[ks][2]=g0.z; gs[ks][3]=g0.w;
    gs[ks][4]=g1.x; gs[ks][5]=g1.y; gs[ks][6]=g1.z; gs[ks][7]=g1.w;
  }

  s8v ah[2][2], al[2][2];
  #pragma unroll
  for (int mt = 0; mt < 2; ++mt) {
    const float* vr = V + (size_t)(mt ? j1 : j0) * 64;
    #pragma unroll
    for (int ks = 0; ks < 2; ++ks) {
      int cb = ks*32 + kb*8;
      float4 v0 = *(const float4*)&vr[cb];
      float4 v1 = *(const float4*)&vr[cb + 4];
      float hv[8];
      hv[0]=base[ks][0]+v0.x*gs[ks][0]; hv[1]=base[ks][1]+v0.y*gs[ks][1];
      hv[2]=base[ks][2]+v0.z*gs[ks][2]; hv[3]=base[ks][3]+v0.w*gs[ks][3];
      hv[4]=base[ks][4]+v1.x*gs[ks][4]; hv[5]=base[ks][5]+v1.y*gs[ks][5];
      hv[6]=base[ks][6]+v1.z*gs[ks][6]; hv[7]=base[ks][7]+v1.w*gs[ks][7];
      s8v hfrag, lfrag;
      #pragma unroll
      for (int e = 0; e < 8; ++e) {
        float h1 = hv[e] > 0.f ? hv[e] : 0.f;
        u16 hh, ll;
        cvt_split(h1, hh, ll);
        hfrag[e] = (short)hh; lfrag[e] = (short)ll;
      }
      ah[mt][ks] = hfrag; al[mt][ks] = lfrag;
    }
  }

  f4v acc[2][4];
  #pragma unroll
  for (int mt = 0; mt < 2; ++mt)
    #pragma unroll
    for (int jf = 0; jf < 4; ++jf) acc[mt][jf] = (f4v)(0.f);

  #pragma unroll
  for (int mt = 0; mt < 2; ++mt)
    #pragma unroll
    for (int jf = 0; jf < 4; ++jf)
      #pragma unroll
      for (int ks = 0; ks < 2; ++ks) {
        acc[mt][jf] = __builtin_amdgcn_mfma_f32_16x16x32_bf16(ah[mt][ks], bh[jf][ks], acc[mt][jf], 0, 0, 0);
        acc[mt][jf] = __builtin_amdgcn_mfma_f32_16x16x32_bf16(ah[mt][ks], bl[jf][ks], acc[mt][jf], 0, 0, 0);
        acc[mt][jf] = __builtin_amdgcn_mfma_f32_16x16x32_bf16(al[mt][ks], bh[jf][ks], acc[mt][jf], 0, 0, 0);
      }

  #pragma unroll
  for (int jf = 0; jf < 4; ++jf) {
    float m = fmaxf(fmaxf(acc[0][jf][0], acc[0][jf][1]), fmaxf(acc[0][jf][2], acc[0][jf][3]));
    float m1 = fmaxf(fmaxf(acc[1][jf][0], acc[1][jf][1]), fmaxf(acc[1][jf][2], acc[1][jf][3]));
    m = fmaxf(m, m1);
    m = fmaxf(m, __shfl_xor(m, 16));
    m = fmaxf(m, __shfl_xor(m, 32));
    if (kb == 0) out[(size_t)p*ostride + jf*16 + lr] = m + b2[jf*16 + lr];
  }
}

// ---------------- split-bf16 MFMA GEMM v2: no LDS, pre-split A and W, fragments from L2 ----------------
// C = relu(A@W + b); SPLIT=1: write u16 hi/lo pair (feeds next layer); SPLIT=0: write f32
template<int NJF, int SPLIT>
__global__ __launch_bounds__(256) void k_mlp(
    const u16* __restrict__ Ahg, const u16* __restrict__ Alg, int lka,
    const u16* __restrict__ Wth, const u16* __restrict__ Wtl, int PKW,
    const float* __restrict__ bg,
    float* __restrict__ Cf, u16* __restrict__ Ch, u16* __restrict__ Cl,
    int ldc, int K) {
  int tid  = threadIdx.x;
  int wave = tid >> 6, lane = tid & 63;
  int wm = (wave >> 1) * 64, wn = (wave & 1) * (NJF*16);
  int lr = lane & 15, kb = lane >> 4;
  int m0 = blockIdx.y * 128, n0 = blockIdx.x * (2*NJF*16);

  f4v acc[4][NJF];
  #pragma unroll
  for (int i = 0; i < 4; ++i)
    #pragma unroll
    for (int j = 0; j < NJF; ++j) acc[i][j] = (f4v)(0.f);

  for (int k0 = 0; k0 < K; k0 += 32) {
    s8v bh[NJF], bl[NJF], ah[4], al[4];
    #pragma unroll
    for (int jf = 0; jf < NJF; ++jf) {
      int n = n0 + wn + jf*16 + lr;
      bh[jf] = *(const s8v*)&Wth[(size_t)n*PKW + k0 + kb*8];
      bl[jf] = *(const s8v*)&Wtl[(size_t)n*PKW + k0 + kb*8];
    }
    #pragma unroll
    for (int mf = 0; mf < 4; ++mf) {
      size_t a = (size_t)(m0 + wm + mf*16 + lr)*lka + k0 + kb*8;
      ah[mf] = *(const s8v*)&Ahg[a];
      al[mf] = *(const s8v*)&Alg[a];
    }
    #pragma unroll
    for (int mf = 0; mf < 4; ++mf)
      #pragma unroll
      for (int jf = 0; jf < NJF; ++jf) {
        acc[mf][jf] = __builtin_amdgcn_mfma_f32_16x16x32_bf16(ah[mf], bh[jf], acc[mf][jf], 0, 0, 0);
        acc[mf][jf] = __builtin_amdgcn_mfma_f32_16x16x32_bf16(ah[mf], bl[jf], acc[mf][jf], 0, 0, 0);
        acc[mf][jf] = __builtin_amdgcn_mfma_f32_16x16x32_bf16(al[mf], bh[jf], acc[mf][jf], 0, 0, 0);
      }
  }

  #pragma unroll
  for (int jf = 0; jf < NJF; ++jf) {
    int n = n0 + wn + jf*16 + lr;
    float bb = bg[n];
    #pragma unroll
    for (int mf = 0; mf < 4; ++mf) {
      #pragma unroll
      for (int r = 0; r < 4; ++r) {
        int m = m0 + wm + mf*16 + kb*4 + r;
        float v = acc[mf][jf][r] + bb;
        v = v > 0.f ? v : 0.f;
        if (SPLIT) {
          u16 h, l;
          cvt_split(v, h, l);
          Ch[(size_t)m*ldc + n] = h;
          Cl[(size_t)m*ldc + n] = l;
        } else {
          Cf[(size_t)m*ldc + n] = v;
        }
      }
    }
  }
}

// ---------------- head: 128->13 + log_softmax, lane per point ----------------
__global__ __launch_bounds__(256) void k_head(const float* __restrict__ H3,
    const float* __restrict__ W4, const float* __restrict__ b4,
    float* __restrict__ out0, int pbase) {
  __shared__ float w4s[128 * 13];
  __shared__ float b4s[13];
  for (int e = threadIdx.x; e < 128*13; e += 256) w4s[e] = W4[e];
  if (threadIdx.x < 13) b4s[threadIdx.x] = b4[threadIdx.x];
  __syncthreads();
  int pl = blockIdx.x * 256 + threadIdx.x;
  float acc[13];
  #pragma unroll
  for (int c = 0; c < 13; ++c) acc[c] = b4s[c];
  const float* hr = H3 + (size_t)pl * 128;
  #pragma unroll 1
  for (int k = 0; k < 128; k += 4) {
    float4 h = *(const float4*)&hr[k];
    #pragma unroll
    for (int c = 0; c < 13; ++c) {
      acc[c] += h.x * w4s[(k+0)*13 + c];
      acc[c] += h.y * w4s[(k+1)*13 + c];
      acc[c] += h.z * w4s[(k+2)*13 + c];
      acc[c] += h.w * w4s[(k+3)*13 + c];
    }
  }
  float mx = acc[0];
  #pragma unroll
  for (int c = 1; c < 13; ++c) mx = fmaxf(mx, acc[c]);
  float s = 0.f;
  #pragma unroll
  for (int c = 0; c < 13; ++c) s += expf(acc[c] - mx);
  float lg = logf(s);
  size_t ob = (size_t)(pbase + pl) * 13;
  #pragma unroll
  for (int c = 0; c < 13; ++c) out0[ob + c] = acc[c] - mx - lg;
}

// ---------------- out1 = x3 ----------------
__global__ void k_out1(const float* __restrict__ hcat, float* __restrict__ out1) {
  int e = blockIdx.x * 256 + threadIdx.x;
  int p = e >> 6, c = e & 63;
  out1[e] = hcat[(size_t)p*192 + 128 + c];
}

extern "C" void kernel_launch(void* const* d_in, const int* in_sizes, int n_in,
                              void* d_out, int out_size, void* d_ws, size_t ws_size,
                              hipStream_t stream) {
  (void)in_sizes; (void)n_in; (void)out_size; (void)ws_size;
  const float* x   = (const float*)d_in[0];
  const float* pos = (const float*)d_in[1];
  const float* cw[3][6];   // W1,b1,g,be,W2,b2 per conv
  for (int c = 0; c < 3; ++c)
    for (int t = 0; t < 6; ++t)
      cw[c][t] = (const float*)d_in[3 + c*6 + t];
  const float *mW[4], *mb[4];
  for (int j = 0; j < 4; ++j) {
    mW[j] = (const float*)d_in[21 + 2*j];
    mb[j] = (const float*)d_in[22 + 2*j];
  }

  float* ws   = (float*)d_ws;
  float* x0   = ws;                        // 131072
  float* sq   = x0 + 131072;               // 16384
  int*   knn  = (int*)(sq + 16384);        // 491520 ints
  float* A0   = (float*)(knn + 491520);    // 1048576 (4 MB)
  float* V    = A0 + 1048576;              // 1048576 (4 MB)
  float* hcat = V + 1048576;               // 3145728 (x1|x2|x3, stride 192)
  float* U    = hcat + 3145728;            // 8388608 (D chunks; later H1h|H1l u16)
  float* H2c  = U + 8388608;               // 2097152 (H2h|H2l u16)
  float* H3c  = H2c + 2097152;             // 1048576 (f32, head input)
  u16*   eW2  = (u16*)(H3c + 1048576);     // conv3 W2 split: 2 x 4608 u16
  float* wd1  = (float*)(eW2 + 9216);      // conv1 Wd: 384
  float* wd2  = wd1 + 384;                 // conv2 Wd: 4096
  float* wd3  = wd2 + 4096;                // conv3 Wd: 4096

  // MLP weight splits: second half of V region (dead after conv phase)
  u16* mwp = (u16*)(V + 524288);           // 2 MB area
  u16* m1h = mwp;            u16* m1l = m1h + 204800;   // [1024][200]
  u16* m2h = m1l + 204800;   u16* m2l = m2h + 264192;   // [256][1032]
  u16* m3h = m2l + 264192;   u16* m3l = m3h + 33792;    // [128][264]
  // per-ch activation split: A0 region + first half of V (dead after conv phase)
  u16* Aih = (u16*)A0;                     // 8192*192 u16
  u16* Ail = Aih + 1572864;                // ends exactly at V + 524288 floats
  // H1/H2 splits
  u16* H1h = (u16*)U;        u16* H1l = H1h + 8388608;  // [8192][1024] each
  u16* H2h = (u16*)H2c;      u16* H2l = H2h + 2097152;  // [8192][256] each

  float* out0 = (float*)d_out;
  float* out1 = out0 + 8*2048*13;

  k_misc0<<<83, 256, 0, stream>>>(x, pos, x0, sq, cw[2][4], eW2, eW2 + 4608,
                                  cw[0][0], cw[1][0], cw[2][0], wd1, wd2, wd3);

  for (int c = 0; c < 3; ++c) {
    const float* xin; const float* wdc; int stride, F;
    if (c == 0)      { xin = x0;        wdc = wd1; stride = 8;   F = 6;  }
    else if (c == 1) { xin = hcat;      wdc = wd2; stride = 192; F = 64; }
    else             { xin = hcat + 64; wdc = wd3; stride = 192; F = 64; }
    if (c > 0)
      k_sqnorm<<<4096, 256, 0, stream>>>(xin, 192, 64, sq);   // conv1 sq comes from k_misc0
    for (int ch = 0; ch < 4; ++ch) {
      if (c == 0) k_dist<8> <<<dim3(16,4,8), 256, 0, stream>>>(xin, stride, sq, ch*512, U);
      else        k_dist<64><<<dim3(16,4,8), 256, 0, stream>>>(xin, stride, sq, ch*512, U);
      k_topk<<<1024, 256, 0, stream>>>(U, ch*512, knn);
    }
    k_prep<<<4096, 256, 0, stream>>>(xin, stride, F, wdc, cw[c][0], cw[c][1], A0, V);
    if (c < 2)
      k_edge_b<<<4096, 256, 0, stream>>>(A0, V, knn, cw[c][4], cw[c][5],
                                         cw[c][2], cw[c][3], hcat + 64*c, 192);
    else
      k_edge_m<<<4096, 256, 0, stream>>>(A0, V, knn, eW2, eW2 + 4608,
                                         cw[c][5], cw[c][2], cw[c][3], hcat + 64*c, 192);
  }

  // split MLP weights (V region second half now dead)
  k_splitmlp<<<1920, 256, 0, stream>>>(mW[0], mW[1], mW[2], m1h, m1l, m2h, m2l, m3h, m3l);

  for (int ch = 0; ch < 2; ++ch) {
    k_splita<<<6144, 256, 0, stream>>>(hcat + (size_t)ch * 8192 * 192, Aih, Ail);
    k_mlp<4,1><<<dim3(8,64), 256, 0, stream>>>(Aih, Ail, 192,  m1h, m1l, 200,  mb[0],
                                               nullptr, H1h, H1l, 1024, 192);
    k_mlp<2,1><<<dim3(4,64), 256, 0, stream>>>(H1h, H1l, 1024, m2h, m2l, 1032, mb[1],
                                               nullptr, H2h, H2l, 256, 1024);
    k_mlp<2,0><<<dim3(2,64), 256, 0, stream>>>(H2h, H2l, 256,  m3h, m3l, 264,  mb[2],
                                               H3c, nullptr, nullptr, 128, 256);
    k_head<<<32, 256, 0, stream>>>(H3c, mW[3], mb[3], out0, ch*8192);
  }
  k_out1<<<4096, 256, 0, stream>>>(hcat, out1);
}